// Round 1
// baseline (1286.535 us; speedup 1.0000x reference)
//
#include <hip/hip_runtime.h>

#define N_TOK 8192
#define DDIM  1024
#define HDIM  4096
#define NEXP  6

typedef unsigned short ushort_t;
typedef __bf16 bf16_t;
typedef bf16_t bf16x8 __attribute__((ext_vector_type(8)));
typedef float f32x4 __attribute__((ext_vector_type(4)));

typedef const __attribute__((address_space(1))) void* gptr_t;
typedef __attribute__((address_space(3))) void* lptr_t;

__device__ __forceinline__ void g2l16(const void* g, void* l) {
    __builtin_amdgcn_global_load_lds((gptr_t)g, (lptr_t)l, 16, 0, 0);
}

__device__ __forceinline__ ushort_t f2bf(float f) {
    unsigned int u = __float_as_uint(f);
    unsigned int r = (u + 0x7FFFu + ((u >> 16) & 1u)) >> 16;
    return (ushort_t)r;
}

// ---------------- convert x: fp32 -> bf16 ----------------
__global__ void convert_x_kernel(const float* __restrict__ x, ushort_t* __restrict__ xb) {
    size_t i = (size_t)(blockIdx.x * 256 + threadIdx.x) * 8;
    float4 a = *(const float4*)(x + i);
    float4 b = *(const float4*)(x + i + 4);
    union { ushort_t u[8]; uint4 v; } o;
    o.u[0] = f2bf(a.x); o.u[1] = f2bf(a.y); o.u[2] = f2bf(a.z); o.u[3] = f2bf(a.w);
    o.u[4] = f2bf(b.x); o.u[5] = f2bf(b.y); o.u[6] = f2bf(b.z); o.u[7] = f2bf(b.w);
    *(uint4*)(xb + i) = o.v;
}

// ---------------- transpose + convert: src (R,C) fp32 -> dst (C,R) bf16, per expert z ----------------
__global__ void transpose_bf16_kernel(const float* __restrict__ src, ushort_t* __restrict__ dst,
                                      int R, int C) {
    __shared__ float tile[32][33];
    size_t msz = (size_t)R * C;
    src += (size_t)blockIdx.z * msz;
    dst += (size_t)blockIdx.z * msz;
    int c0 = blockIdx.x * 32, r0 = blockIdx.y * 32;
    int tx = threadIdx.x & 31, ty = threadIdx.x >> 5;  // 32 x 8
#pragma unroll
    for (int i = 0; i < 4; ++i)
        tile[ty + 8 * i][tx] = src[(size_t)(r0 + ty + 8 * i) * C + c0 + tx];
    __syncthreads();
#pragma unroll
    for (int i = 0; i < 4; ++i)
        dst[(size_t)(c0 + ty + 8 * i) * R + r0 + tx] = f2bf(tile[tx][ty + 8 * i]);
}

// ---------------- router: one wave per token ----------------
__global__ void router_kernel(const float* __restrict__ x, const float* __restrict__ wr,
                              int* __restrict__ tok_e, float* __restrict__ tok_w,
                              float* __restrict__ probsums, int* __restrict__ counts) {
    int wid = threadIdx.x >> 6, l = threadIdx.x & 63;
    int t = blockIdx.x * 4 + wid;
    const float* xr = x + (size_t)t * DDIM;
    float acc[NEXP] = {0.f, 0.f, 0.f, 0.f, 0.f, 0.f};
#pragma unroll
    for (int c = 0; c < 4; ++c) {
        int k0 = c * 256 + l * 4;
        float4 xv = *(const float4*)(xr + k0);
        float wv[24];
#pragma unroll
        for (int q = 0; q < 6; ++q)
            *(float4*)(wv + 4 * q) = *(const float4*)(wr + (size_t)k0 * NEXP + 4 * q);
        float xa[4] = {xv.x, xv.y, xv.z, xv.w};
#pragma unroll
        for (int r = 0; r < 4; ++r)
#pragma unroll
            for (int e = 0; e < NEXP; ++e) acc[e] += xa[r] * wv[r * NEXP + e];
    }
#pragma unroll
    for (int e = 0; e < NEXP; ++e)
#pragma unroll
        for (int d = 32; d >= 1; d >>= 1) acc[e] += __shfl_xor(acc[e], d);
    if (l == 0) {
        float m = acc[0];
#pragma unroll
        for (int e = 1; e < NEXP; ++e) m = fmaxf(m, acc[e]);
        float p[NEXP], s = 0.f;
#pragma unroll
        for (int e = 0; e < NEXP; ++e) { p[e] = __expf(acc[e] - m); s += p[e]; }
        // use precise expf to match reference closely
        s = 0.f;
#pragma unroll
        for (int e = 0; e < NEXP; ++e) { p[e] = expf(acc[e] - m); s += p[e]; }
        float inv = 1.0f / s;
#pragma unroll
        for (int e = 0; e < NEXP; ++e) p[e] *= inv;
        int i1 = 0; float b1 = p[0];
#pragma unroll
        for (int e = 1; e < NEXP; ++e) if (p[e] > b1) { b1 = p[e]; i1 = e; }
        int i2 = -1; float b2 = -1.f;
#pragma unroll
        for (int e = 0; e < NEXP; ++e) if (e != i1 && p[e] > b2) { b2 = p[e]; i2 = e; }
        float swn = 1.0f / (b1 + b2);
        tok_e[2 * t] = i1; tok_e[2 * t + 1] = i2;
        tok_w[2 * t] = b1 * swn; tok_w[2 * t + 1] = b2 * swn;
        atomicAdd(&counts[i1], 1);
        atomicAdd(&counts[i2], 1);
#pragma unroll
        for (int e = 0; e < NEXP; ++e) atomicAdd(&probsums[e], p[e]);
    }
}

// ---------------- finalize: offsets + aux loss ----------------
__global__ void finalize_kernel(const int* __restrict__ counts, int* __restrict__ offs,
                                const float* __restrict__ probsums, float* __restrict__ aux_out) {
    if (threadIdx.x == 0) {
        int o = 0;
        for (int e = 0; e < NEXP; ++e) { offs[e] = o; o += counts[e]; }
        offs[NEXP] = o;
        float s = 0.f;
        for (int e = 0; e < NEXP; ++e) {
            float t = probsums[e] / (float)N_TOK - (1.0f / 6.0f);
            s += t * t;
        }
        aux_out[0] = 0.01f * (s / 6.0f);
    }
}

// ---------------- scatter tokens into expert-sorted slot lists ----------------
__global__ void scatter_kernel(const int* __restrict__ tok_e, const float* __restrict__ tok_w,
                               const int* __restrict__ offs, int* __restrict__ cursors,
                               int* __restrict__ slot_token, float* __restrict__ slot_w) {
    int t = blockIdx.x * 256 + threadIdx.x;
    if (t >= N_TOK) return;
#pragma unroll
    for (int s = 0; s < 2; ++s) {
        int e = tok_e[2 * t + s];
        int pos = atomicAdd(&cursors[e], 1);
        int idx = offs[e] + pos;
        slot_token[idx] = t;
        slot_w[idx] = tok_w[2 * t + s];
    }
}

// ---------------- MoE GEMM: 128x128 tile, BK=32, 4 waves, 16x16x32 bf16 MFMA ----------------
// LAYER 1: h[slot] = gelu(x[tok] @ w1T^T), A gathered by slot_token.  Nd=HDIM, Kd=DDIM.
// LAYER 2: out[tok] += w_slot * (h[slot] @ w2T^T).                    Nd=DDIM, Kd=HDIM.
template <int LAYER>
__global__ __launch_bounds__(256, 2)
void moe_gemm_kernel(const ushort_t* __restrict__ A, const ushort_t* __restrict__ Bt,
                     ushort_t* __restrict__ Hout, float* __restrict__ Out,
                     const int* __restrict__ slot_token, const float* __restrict__ slot_w,
                     const int* __restrict__ offs, const int* __restrict__ counts) {
    constexpr int Kd = (LAYER == 1) ? DDIM : HDIM;
    constexpr int Nd = (LAYER == 1) ? HDIM : DDIM;
    const int e = blockIdx.z;
    const int cnt = counts[e];
    const int mbase = blockIdx.y * 128;
    if (mbase >= cnt) return;
    const int nbase = blockIdx.x * 128;
    const int off = offs[e];
    const ushort_t* Bte = Bt + (size_t)e * ((size_t)Nd * Kd);

    __shared__ __align__(16) ushort_t lds[8192];  // A: elems [0,4096), B: [4096,8192)

    const int tid = threadIdx.x;
    const int wid = tid >> 6, l = tid & 63;

    // staging source offsets (elements). chunk = j*256+tid -> LDS row=chunk>>2, slot=chunk&3.
    // swizzle: slot s at LDS row holds logical k-group kg = s ^ ((row>>1)&3)  (2-way bank aliasing = free)
    size_t aoff[2], boff[2];
#pragma unroll
    for (int j = 0; j < 2; ++j) {
        int row = (j * 256 + tid) >> 2;
        int slot = tid & 3;
        int kg = slot ^ ((row >> 1) & 3);
        int lr = mbase + row;
        int lrc = lr < cnt - 1 ? lr : cnt - 1;
        size_t arow;
        if (LAYER == 1) arow = (size_t)slot_token[off + lrc] * DDIM;
        else            arow = (size_t)(off + lrc) * HDIM;
        aoff[j] = arow + (size_t)kg * 8;
        boff[j] = (size_t)(nbase + row) * Kd + (size_t)kg * 8;
    }
    // wave-uniform LDS staging bases (elements): base = j*2048 + wid*512 (+4096 for B)
    ushort_t* ldsA0 = lds + wid * 512;
    ushort_t* ldsA1 = lds + 2048 + wid * 512;
    ushort_t* ldsB0 = lds + 4096 + wid * 512;
    ushort_t* ldsB1 = lds + 6144 + wid * 512;

    // fragment read byte offsets (loop-invariant)
    const int lm = l & 15, kg = l >> 4;
    const char* ldsAb = (const char*)lds;
    const char* ldsBb = (const char*)(lds + 4096);
    const int wm = (wid & 1) * 64, wn = (wid >> 1) * 64;
    int arowb[4], browb[4];
#pragma unroll
    for (int f = 0; f < 4; ++f) {
        int ar = wm + f * 16 + lm;
        arowb[f] = ar * 64 + ((kg ^ ((ar >> 1) & 3)) << 4);
        int br = wn + f * 16 + lm;
        browb[f] = br * 64 + ((kg ^ ((br >> 1) & 3)) << 4);
    }

    f32x4 acc[4][4] = {};

    for (int kt = 0; kt < Kd; kt += 32) {
        g2l16(A + aoff[0] + kt, ldsA0);
        g2l16(A + aoff[1] + kt, ldsA1);
        g2l16(Bte + boff[0] + kt, ldsB0);
        g2l16(Bte + boff[1] + kt, ldsB1);
        __syncthreads();
        bf16x8 af[4], bfv[4];
#pragma unroll
        for (int f = 0; f < 4; ++f) {
            af[f]  = *(const bf16x8*)(ldsAb + arowb[f]);
            bfv[f] = *(const bf16x8*)(ldsBb + browb[f]);
        }
#pragma unroll
        for (int i = 0; i < 4; ++i)
#pragma unroll
            for (int jj = 0; jj < 4; ++jj)
                acc[i][jj] = __builtin_amdgcn_mfma_f32_16x16x32_bf16(af[i], bfv[jj], acc[i][jj], 0, 0, 0);
        __syncthreads();
    }

    // epilogue. C/D layout: col = lane&15, row = (lane>>4)*4 + reg
    if (LAYER == 1) {
#pragma unroll
        for (int i = 0; i < 4; ++i) {
#pragma unroll
            for (int r = 0; r < 4; ++r) {
                int row = wm + i * 16 + kg * 4 + r;
                int grow = mbase + row;
                if (grow < cnt) {
                    size_t hbase = (size_t)(off + grow) * HDIM + nbase + wn + lm;
#pragma unroll
                    for (int jj = 0; jj < 4; ++jj) {
                        float v = acc[i][jj][r];
                        float g = 0.5f * v * (1.0f + erff(v * 0.70710678118654752f));
                        Hout[hbase + jj * 16] = f2bf(g);
                    }
                }
            }
        }
    } else {
#pragma unroll
        for (int i = 0; i < 4; ++i) {
#pragma unroll
            for (int r = 0; r < 4; ++r) {
                int row = wm + i * 16 + kg * 4 + r;
                int grow = mbase + row;
                if (grow < cnt) {
                    int si = off + grow;
                    int tok = slot_token[si];
                    float wgt = slot_w[si];
                    float* obase = Out + (size_t)tok * DDIM + nbase + wn + lm;
#pragma unroll
                    for (int jj = 0; jj < 4; ++jj)
                        atomicAdd(obase + jj * 16, wgt * acc[i][jj][r]);
                }
            }
        }
    }
}

extern "C" void kernel_launch(void* const* d_in, const int* in_sizes, int n_in,
                              void* d_out, int out_size, void* d_ws, size_t ws_size,
                              hipStream_t stream) {
    const float* x  = (const float*)d_in[0];
    const float* wr = (const float*)d_in[1];
    const float* w1 = (const float*)d_in[2];
    const float* w2 = (const float*)d_in[3];
    float* out = (float*)d_out;

    // workspace layout (needs ~252 MB)
    char* ws = (char*)d_ws;
    size_t o = 0;
    ushort_t* xb   = (ushort_t*)(ws + o); o += (size_t)N_TOK * DDIM * 2;          // 16 MB
    ushort_t* w1t  = (ushort_t*)(ws + o); o += (size_t)NEXP * HDIM * DDIM * 2;    // 48 MB
    ushort_t* w2t  = (ushort_t*)(ws + o); o += (size_t)NEXP * DDIM * HDIM * 2;    // 48 MB
    ushort_t* hbuf = (ushort_t*)(ws + o); o += (size_t)2 * N_TOK * HDIM * 2;      // 128 MB
    int*   tok_e   = (int*)(ws + o);   o += (size_t)N_TOK * 2 * 4;
    float* tok_w   = (float*)(ws + o); o += (size_t)N_TOK * 2 * 4;
    int*   slot_token = (int*)(ws + o);   o += (size_t)2 * N_TOK * 4;
    float* slot_w     = (float*)(ws + o); o += (size_t)2 * N_TOK * 4;
    int*   counts  = (int*)(ws + o);   o += 32;
    int*   cursors = (int*)(ws + o);   o += 32;
    int*   offs    = (int*)(ws + o);   o += 32;
    float* probsums = (float*)(ws + o); o += 32;

    hipMemsetAsync(d_out, 0, (size_t)out_size * sizeof(float), stream);
    hipMemsetAsync(counts, 0, 128, stream);  // counts/cursors/offs/probsums contiguous

    convert_x_kernel<<<dim3(N_TOK * DDIM / 8 / 256), 256, 0, stream>>>(x, xb);
    transpose_bf16_kernel<<<dim3(HDIM / 32, DDIM / 32, NEXP), 256, 0, stream>>>(w1, w1t, DDIM, HDIM);
    transpose_bf16_kernel<<<dim3(DDIM / 32, HDIM / 32, NEXP), 256, 0, stream>>>(w2, w2t, HDIM, DDIM);
    router_kernel<<<dim3(N_TOK / 4), 256, 0, stream>>>(x, wr, tok_e, tok_w, probsums, counts);
    finalize_kernel<<<dim3(1), 64, 0, stream>>>(counts, offs, probsums, out + (size_t)N_TOK * DDIM);
    scatter_kernel<<<dim3(N_TOK / 256), 256, 0, stream>>>(tok_e, tok_w, offs, cursors, slot_token, slot_w);
    moe_gemm_kernel<1><<<dim3(HDIM / 128, N_TOK / 128, NEXP), 256, 0, stream>>>(
        xb, w1t, hbuf, nullptr, slot_token, slot_w, offs, counts);
    moe_gemm_kernel<2><<<dim3(DDIM / 128, N_TOK / 128, NEXP), 256, 0, stream>>>(
        hbuf, w2t, nullptr, out, slot_token, slot_w, offs, counts);
}

// Round 2
// 567.523 us; speedup vs baseline: 2.2669x; 2.2669x over previous
//
#include <hip/hip_runtime.h>

#define N_TOK 8192
#define DDIM  1024
#define HDIM  4096
#define NEXP  6
#define RBLOCKS (N_TOK / 4)   // router blocks (4 tokens/block)
#define SBLOCKS 32            // scatter blocks (256 tokens/block)

typedef unsigned short ushort_t;
typedef __bf16 bf16_t;
typedef bf16_t bf16x8 __attribute__((ext_vector_type(8)));
typedef float f32x4 __attribute__((ext_vector_type(4)));

typedef const __attribute__((address_space(1))) void* gptr_t;
typedef __attribute__((address_space(3))) void* lptr_t;

__device__ __forceinline__ void g2l16(const void* g, void* l) {
    __builtin_amdgcn_global_load_lds((gptr_t)g, (lptr_t)l, 16, 0, 0);
}

__device__ __forceinline__ ushort_t f2bf(float f) {
    unsigned int u = __float_as_uint(f);
    unsigned int r = (u + 0x7FFFu + ((u >> 16) & 1u)) >> 16;
    return (ushort_t)r;
}

// ---------------- convert x: fp32 -> bf16 ----------------
__global__ void convert_x_kernel(const float* __restrict__ x, ushort_t* __restrict__ xb) {
    size_t i = (size_t)(blockIdx.x * 256 + threadIdx.x) * 8;
    float4 a = *(const float4*)(x + i);
    float4 b = *(const float4*)(x + i + 4);
    union { ushort_t u[8]; uint4 v; } o;
    o.u[0] = f2bf(a.x); o.u[1] = f2bf(a.y); o.u[2] = f2bf(a.z); o.u[3] = f2bf(a.w);
    o.u[4] = f2bf(b.x); o.u[5] = f2bf(b.y); o.u[6] = f2bf(b.z); o.u[7] = f2bf(b.w);
    *(uint4*)(xb + i) = o.v;
}

// ---------------- transpose + convert: src (R,C) fp32 -> dst (C,R) bf16, per expert z ----------------
__global__ void transpose_bf16_kernel(const float* __restrict__ src, ushort_t* __restrict__ dst,
                                      int R, int C) {
    __shared__ float tile[32][33];
    size_t msz = (size_t)R * C;
    src += (size_t)blockIdx.z * msz;
    dst += (size_t)blockIdx.z * msz;
    int c0 = blockIdx.x * 32, r0 = blockIdx.y * 32;
    int tx = threadIdx.x & 31, ty = threadIdx.x >> 5;  // 32 x 8
#pragma unroll
    for (int i = 0; i < 4; ++i)
        tile[ty + 8 * i][tx] = src[(size_t)(r0 + ty + 8 * i) * C + c0 + tx];
    __syncthreads();
#pragma unroll
    for (int i = 0; i < 4; ++i)
        dst[(size_t)(c0 + ty + 8 * i) * R + r0 + tx] = f2bf(tile[tx][ty + 8 * i]);
}

// ---------------- router: one wave per token; block-local reduction, NO global atomics ----------------
__global__ void router_kernel(const float* __restrict__ x, const float* __restrict__ wr,
                              int* __restrict__ tok_e, float* __restrict__ tok_w,
                              float* __restrict__ part_p, int* __restrict__ part_c) {
    __shared__ float bsum[NEXP];
    __shared__ int bcnt[NEXP];
    int wid = threadIdx.x >> 6, l = threadIdx.x & 63;
    if (threadIdx.x < NEXP) { bsum[threadIdx.x] = 0.f; bcnt[threadIdx.x] = 0; }
    __syncthreads();
    int t = blockIdx.x * 4 + wid;
    const float* xr = x + (size_t)t * DDIM;
    float acc[NEXP] = {0.f, 0.f, 0.f, 0.f, 0.f, 0.f};
#pragma unroll
    for (int c = 0; c < 4; ++c) {
        int k0 = c * 256 + l * 4;
        float4 xv = *(const float4*)(xr + k0);
        float wv[24];
#pragma unroll
        for (int q = 0; q < 6; ++q)
            *(float4*)(wv + 4 * q) = *(const float4*)(wr + (size_t)k0 * NEXP + 4 * q);
        float xa[4] = {xv.x, xv.y, xv.z, xv.w};
#pragma unroll
        for (int r = 0; r < 4; ++r)
#pragma unroll
            for (int e = 0; e < NEXP; ++e) acc[e] += xa[r] * wv[r * NEXP + e];
    }
#pragma unroll
    for (int e = 0; e < NEXP; ++e)
#pragma unroll
        for (int d = 32; d >= 1; d >>= 1) acc[e] += __shfl_xor(acc[e], d);
    if (l == 0) {
        float m = acc[0];
#pragma unroll
        for (int e = 1; e < NEXP; ++e) m = fmaxf(m, acc[e]);
        float p[NEXP], s = 0.f;
#pragma unroll
        for (int e = 0; e < NEXP; ++e) { p[e] = expf(acc[e] - m); s += p[e]; }
        float inv = 1.0f / s;
#pragma unroll
        for (int e = 0; e < NEXP; ++e) p[e] *= inv;
        int i1 = 0; float b1 = p[0];
#pragma unroll
        for (int e = 1; e < NEXP; ++e) if (p[e] > b1) { b1 = p[e]; i1 = e; }
        int i2 = -1; float b2 = -1.f;
#pragma unroll
        for (int e = 0; e < NEXP; ++e) if (e != i1 && p[e] > b2) { b2 = p[e]; i2 = e; }
        float swn = 1.0f / (b1 + b2);
        tok_e[2 * t] = i1; tok_e[2 * t + 1] = i2;
        tok_w[2 * t] = b1 * swn; tok_w[2 * t + 1] = b2 * swn;
        atomicAdd(&bcnt[i1], 1);
        atomicAdd(&bcnt[i2], 1);
#pragma unroll
        for (int e = 0; e < NEXP; ++e) atomicAdd(&bsum[e], p[e]);
    }
    __syncthreads();
    if (threadIdx.x < NEXP) {
        part_p[(size_t)blockIdx.x * NEXP + threadIdx.x] = bsum[threadIdx.x];
        part_c[(size_t)blockIdx.x * NEXP + threadIdx.x] = bcnt[threadIdx.x];
    }
}

// ---------------- finalize: reduce partials -> counts/offsets + aux loss ----------------
__global__ void finalize_kernel(const float* __restrict__ part_p, const int* __restrict__ part_c,
                                int* __restrict__ counts, int* __restrict__ offs,
                                float* __restrict__ aux_out) {
    __shared__ float redp[NEXP][4];
    __shared__ int redc[NEXP][4];
    int tid = threadIdx.x, wid = tid >> 6, l = tid & 63;
    float myp[NEXP] = {0.f, 0.f, 0.f, 0.f, 0.f, 0.f};
    int myc[NEXP] = {0, 0, 0, 0, 0, 0};
    for (int b = tid; b < RBLOCKS; b += 256) {
#pragma unroll
        for (int e = 0; e < NEXP; ++e) {
            myp[e] += part_p[(size_t)b * NEXP + e];
            myc[e] += part_c[(size_t)b * NEXP + e];
        }
    }
#pragma unroll
    for (int e = 0; e < NEXP; ++e) {
#pragma unroll
        for (int d = 32; d >= 1; d >>= 1) {
            myp[e] += __shfl_xor(myp[e], d);
            myc[e] += __shfl_xor(myc[e], d);
        }
        if (l == 0) { redp[e][wid] = myp[e]; redc[e][wid] = myc[e]; }
    }
    __syncthreads();
    if (tid == 0) {
        int o = 0;
        float s = 0.f;
        for (int e = 0; e < NEXP; ++e) {
            int c = redc[e][0] + redc[e][1] + redc[e][2] + redc[e][3];
            float ps = redp[e][0] + redp[e][1] + redp[e][2] + redp[e][3];
            counts[e] = c;
            offs[e] = o;
            o += c;
            float d = ps / (float)N_TOK - (1.0f / 6.0f);
            s += d * d;
        }
        offs[NEXP] = o;
        aux_out[0] = 0.01f * (s / 6.0f);
    }
}

// ---------------- scatter: per-block LDS ranking + range reservation (192 global atomics) ----------------
__global__ void scatter_kernel(const int* __restrict__ tok_e, const float* __restrict__ tok_w,
                               const int* __restrict__ offs, int* __restrict__ cursors,
                               int* __restrict__ slot_token, float* __restrict__ slot_w) {
    __shared__ int lcnt[NEXP], lbase[NEXP];
    int tid = threadIdx.x;
    if (tid < NEXP) lcnt[tid] = 0;
    __syncthreads();
    int t = blockIdx.x * 256 + tid;
    int e0 = tok_e[2 * t], e1 = tok_e[2 * t + 1];
    int r0 = atomicAdd(&lcnt[e0], 1);
    int r1 = atomicAdd(&lcnt[e1], 1);
    __syncthreads();
    if (tid < NEXP) lbase[tid] = atomicAdd(&cursors[tid], lcnt[tid]);
    __syncthreads();
    int i0 = offs[e0] + lbase[e0] + r0;
    slot_token[i0] = t; slot_w[i0] = tok_w[2 * t];
    int i1 = offs[e1] + lbase[e1] + r1;
    slot_token[i1] = t; slot_w[i1] = tok_w[2 * t + 1];
}

// ---------------- MoE GEMM: 128x128 tile, BK=32, 4 waves, 16x16x32 bf16 MFMA ----------------
template <int LAYER>
__global__ __launch_bounds__(256, 2)
void moe_gemm_kernel(const ushort_t* __restrict__ A, const ushort_t* __restrict__ Bt,
                     ushort_t* __restrict__ Hout, float* __restrict__ Out,
                     const int* __restrict__ slot_token, const float* __restrict__ slot_w,
                     const int* __restrict__ offs, const int* __restrict__ counts) {
    constexpr int Kd = (LAYER == 1) ? DDIM : HDIM;
    constexpr int Nd = (LAYER == 1) ? HDIM : DDIM;
    const int e = blockIdx.z;
    const int cnt = counts[e];
    const int mbase = blockIdx.y * 128;
    if (mbase >= cnt) return;
    const int nbase = blockIdx.x * 128;
    const int off = offs[e];
    const ushort_t* Bte = Bt + (size_t)e * ((size_t)Nd * Kd);

    __shared__ __align__(16) ushort_t lds[8192];  // A: elems [0,4096), B: [4096,8192)

    const int tid = threadIdx.x;
    const int wid = tid >> 6, l = tid & 63;

    size_t aoff[2], boff[2];
#pragma unroll
    for (int j = 0; j < 2; ++j) {
        int row = (j * 256 + tid) >> 2;
        int slot = tid & 3;
        int kg = slot ^ ((row >> 1) & 3);
        int lr = mbase + row;
        int lrc = lr < cnt - 1 ? lr : cnt - 1;
        size_t arow;
        if (LAYER == 1) arow = (size_t)slot_token[off + lrc] * DDIM;
        else            arow = (size_t)(off + lrc) * HDIM;
        aoff[j] = arow + (size_t)kg * 8;
        boff[j] = (size_t)(nbase + row) * Kd + (size_t)kg * 8;
    }
    ushort_t* ldsA0 = lds + wid * 512;
    ushort_t* ldsA1 = lds + 2048 + wid * 512;
    ushort_t* ldsB0 = lds + 4096 + wid * 512;
    ushort_t* ldsB1 = lds + 6144 + wid * 512;

    const int lm = l & 15, kg = l >> 4;
    const char* ldsAb = (const char*)lds;
    const char* ldsBb = (const char*)(lds + 4096);
    const int wm = (wid & 1) * 64, wn = (wid >> 1) * 64;
    int arowb[4], browb[4];
#pragma unroll
    for (int f = 0; f < 4; ++f) {
        int ar = wm + f * 16 + lm;
        arowb[f] = ar * 64 + ((kg ^ ((ar >> 1) & 3)) << 4);
        int br = wn + f * 16 + lm;
        browb[f] = br * 64 + ((kg ^ ((br >> 1) & 3)) << 4);
    }

    f32x4 acc[4][4] = {};

    for (int kt = 0; kt < Kd; kt += 32) {
        g2l16(A + aoff[0] + kt, ldsA0);
        g2l16(A + aoff[1] + kt, ldsA1);
        g2l16(Bte + boff[0] + kt, ldsB0);
        g2l16(Bte + boff[1] + kt, ldsB1);
        __syncthreads();
        bf16x8 af[4], bfv[4];
#pragma unroll
        for (int f = 0; f < 4; ++f) {
            af[f]  = *(const bf16x8*)(ldsAb + arowb[f]);
            bfv[f] = *(const bf16x8*)(ldsBb + browb[f]);
        }
#pragma unroll
        for (int i = 0; i < 4; ++i)
#pragma unroll
            for (int jj = 0; jj < 4; ++jj)
                acc[i][jj] = __builtin_amdgcn_mfma_f32_16x16x32_bf16(af[i], bfv[jj], acc[i][jj], 0, 0, 0);
        __syncthreads();
    }

    if (LAYER == 1) {
#pragma unroll
        for (int i = 0; i < 4; ++i) {
#pragma unroll
            for (int r = 0; r < 4; ++r) {
                int row = wm + i * 16 + kg * 4 + r;
                int grow = mbase + row;
                if (grow < cnt) {
                    size_t hbase = (size_t)(off + grow) * HDIM + nbase + wn + lm;
#pragma unroll
                    for (int jj = 0; jj < 4; ++jj) {
                        float v = acc[i][jj][r];
                        float g = 0.5f * v * (1.0f + erff(v * 0.70710678118654752f));
                        Hout[hbase + jj * 16] = f2bf(g);
                    }
                }
            }
        }
    } else {
#pragma unroll
        for (int i = 0; i < 4; ++i) {
#pragma unroll
            for (int r = 0; r < 4; ++r) {
                int row = wm + i * 16 + kg * 4 + r;
                int grow = mbase + row;
                if (grow < cnt) {
                    int si = off + grow;
                    int tok = slot_token[si];
                    float wgt = slot_w[si];
                    float* obase = Out + (size_t)tok * DDIM + nbase + wn + lm;
#pragma unroll
                    for (int jj = 0; jj < 4; ++jj)
                        atomicAdd(obase + jj * 16, wgt * acc[i][jj][r]);
                }
            }
        }
    }
}

extern "C" void kernel_launch(void* const* d_in, const int* in_sizes, int n_in,
                              void* d_out, int out_size, void* d_ws, size_t ws_size,
                              hipStream_t stream) {
    const float* x  = (const float*)d_in[0];
    const float* wr = (const float*)d_in[1];
    const float* w1 = (const float*)d_in[2];
    const float* w2 = (const float*)d_in[3];
    float* out = (float*)d_out;

    char* ws = (char*)d_ws;
    size_t o = 0;
    ushort_t* xb   = (ushort_t*)(ws + o); o += (size_t)N_TOK * DDIM * 2;          // 16 MB
    ushort_t* w1t  = (ushort_t*)(ws + o); o += (size_t)NEXP * HDIM * DDIM * 2;    // 48 MB
    ushort_t* w2t  = (ushort_t*)(ws + o); o += (size_t)NEXP * DDIM * HDIM * 2;    // 48 MB
    ushort_t* hbuf = (ushort_t*)(ws + o); o += (size_t)2 * N_TOK * HDIM * 2;      // 128 MB
    int*   tok_e   = (int*)(ws + o);   o += (size_t)N_TOK * 2 * 4;
    float* tok_w   = (float*)(ws + o); o += (size_t)N_TOK * 2 * 4;
    int*   slot_token = (int*)(ws + o);   o += (size_t)2 * N_TOK * 4;
    float* slot_w     = (float*)(ws + o); o += (size_t)2 * N_TOK * 4;
    float* part_p  = (float*)(ws + o); o += (size_t)RBLOCKS * NEXP * 4;           // 48 KB
    int*   part_c  = (int*)(ws + o);   o += (size_t)RBLOCKS * NEXP * 4;           // 48 KB
    int*   counts  = (int*)(ws + o);   o += 32;
    int*   cursors = (int*)(ws + o);   o += 32;
    int*   offs    = (int*)(ws + o);   o += 32;

    hipMemsetAsync(d_out, 0, (size_t)out_size * sizeof(float), stream);
    hipMemsetAsync(cursors, 0, 32, stream);

    convert_x_kernel<<<dim3(N_TOK * DDIM / 8 / 256), 256, 0, stream>>>(x, xb);
    transpose_bf16_kernel<<<dim3(HDIM / 32, DDIM / 32, NEXP), 256, 0, stream>>>(w1, w1t, DDIM, HDIM);
    transpose_bf16_kernel<<<dim3(DDIM / 32, HDIM / 32, NEXP), 256, 0, stream>>>(w2, w2t, HDIM, DDIM);
    router_kernel<<<dim3(RBLOCKS), 256, 0, stream>>>(x, wr, tok_e, tok_w, part_p, part_c);
    finalize_kernel<<<dim3(1), 256, 0, stream>>>(part_p, part_c, counts, offs, out + (size_t)N_TOK * DDIM);
    scatter_kernel<<<dim3(SBLOCKS), 256, 0, stream>>>(tok_e, tok_w, offs, cursors, slot_token, slot_w);
    moe_gemm_kernel<1><<<dim3(HDIM / 128, N_TOK / 128, NEXP), 256, 0, stream>>>(
        xb, w1t, hbuf, nullptr, slot_token, slot_w, offs, counts);
    moe_gemm_kernel<2><<<dim3(DDIM / 128, N_TOK / 128, NEXP), 256, 0, stream>>>(
        hbuf, w2t, nullptr, out, slot_token, slot_w, offs, counts);
}